// Round 1
// baseline (880.944 us; speedup 1.0000x reference)
//
#include <hip/hip_runtime.h>
#include <hip/hip_bf16.h>
#include <stdint.h>

// MultiHeadAttention on MI355X (gfx950), bf16 MFMA pipeline.
// Stages:
//   1. conv_x: x fp32 -> bf16
//   2. transpose_w: Wq/Wk/Wv/Wo fp32 [K x N] -> bf16 W^T [N x K] (packed, w=0..3)
//   3. pack_bias: bq|bk|bv -> [2304]
//   4. gemm<QKV>:  [8192x2304x768] -> q,k [B,H,N,D] bf16, vT [B,H,D,N] bf16
//   5. gemm<SCORES>: per (b,h) [1024x1024x64] *0.125 -> fp32 scores in d_out probs region
//   6. softmax rows in place (d_out probs region)
//   7. gemm<PV>: per (b,h) [1024x64x1024], A = fp32 probs (convert in staging) -> o bf16 [8192x768]
//   8. gemm<OUT>: [8192x768x768] + bo -> d_out fp32
// ws usage ~68 MB.

#define DIM 768
#define NHEADS 12
#define HDIM 64
#define BATCH 8
#define SEQ 1024
#define TOKENS (BATCH * SEQ) /* 8192 */
#define NQKV (3 * DIM)       /* 2304 */

typedef __bf16 bf16x8 __attribute__((ext_vector_type(8)));
typedef float f32x4 __attribute__((ext_vector_type(4)));

__device__ __forceinline__ unsigned int f2bf(float f) {
  unsigned int x = __float_as_uint(f);
  return (x + 0x7fffu + ((x >> 16) & 1u)) >> 16; // RNE bf16, returned in low 16 bits
}

// ---------------- conversion / packing kernels ----------------

__global__ __launch_bounds__(256) void conv_x_kernel(const float* __restrict__ x,
                                                     unsigned short* __restrict__ xb) {
  int i = blockIdx.x * 256 + threadIdx.x; // one float4 per thread
  float4 v = *((const float4*)x + i);
  uint2 o;
  o.x = f2bf(v.x) | (f2bf(v.y) << 16);
  o.y = f2bf(v.z) | (f2bf(v.w) << 16);
  *((uint2*)xb + i) = o;
}

__global__ __launch_bounds__(256) void transpose_w_kernel(const float* __restrict__ Wq,
                                                          const float* __restrict__ Wk,
                                                          const float* __restrict__ Wv,
                                                          const float* __restrict__ Wo,
                                                          unsigned short* __restrict__ WT) {
  __shared__ float tile[32][33];
  const float* W = (blockIdx.z == 0) ? Wq : (blockIdx.z == 1) ? Wk : (blockIdx.z == 2) ? Wv : Wo;
  int tx = threadIdx.x & 31, ty = threadIdx.x >> 5; // 32 x 8
  int k0 = blockIdx.y * 32, n0 = blockIdx.x * 32;
#pragma unroll
  for (int r = ty; r < 32; r += 8) tile[r][tx] = W[(size_t)(k0 + r) * DIM + n0 + tx];
  __syncthreads();
  unsigned short* dst = WT + (size_t)blockIdx.z * DIM * DIM;
#pragma unroll
  for (int r = ty; r < 32; r += 8)
    dst[(size_t)(n0 + r) * DIM + k0 + tx] = (unsigned short)f2bf(tile[tx][r]);
}

__global__ __launch_bounds__(256) void pack_bias_kernel(const float* __restrict__ bq,
                                                        const float* __restrict__ bk,
                                                        const float* __restrict__ bv,
                                                        float* __restrict__ bqkv) {
  int i = blockIdx.x * 256 + threadIdx.x;
  if (i < NQKV) bqkv[i] = (i < DIM) ? bq[i] : (i < 2 * DIM) ? bk[i - DIM] : bv[i - 2 * DIM];
}

// ---------------- generic batched GEMM-BT (bf16 MFMA) ----------------
// C[M x N] = A[M x K] * B^T  with BT[N x K] bf16 row-major.
// Block: 256 thr = 4 waves (2x2), tile 128x128, BK=32, wave tile 64x64 (4x4 MFMA 16x16x32).
// Requirements: M % 128 == 0, K % 32 == 0. N may be ragged (guards on B rows + stores).
// MODE 0 = QKV scatter, 1 = scores (*scale -> fp32, batched), 2 = PV (-> o bf16), 3 = out (+bias fp32)

template <int MODE, typename TA>
__global__ __launch_bounds__(256) void gemm_bt_kernel(
    const TA* __restrict__ A, const unsigned short* __restrict__ B,
    const float* __restrict__ bias, float* __restrict__ outF,
    unsigned short* __restrict__ outA, unsigned short* __restrict__ outB,
    unsigned short* __restrict__ outC, int M, int N, int K, int lda, int ldb,
    long long strideA, long long strideB, float scale) {
  __shared__ alignas(16) unsigned short As[128 * 40]; // pad 32->40 elems: 2-way max conflicts
  __shared__ alignas(16) unsigned short Bs[128 * 40];

  const int z = blockIdx.z;
  A += (long long)z * strideA;
  B += (long long)z * strideB;

  const int t = threadIdx.x;
  const int lane = t & 63;
  const int w = t >> 6;
  const int wm = w >> 1, wn = w & 1;
  const int quad = lane >> 4, l15 = lane & 15;
  const int bm = blockIdx.y, bn = blockIdx.x;

  const f32x4 zero4 = {0.f, 0.f, 0.f, 0.f};
  f32x4 acc[4][4];
#pragma unroll
  for (int i = 0; i < 4; i++)
#pragma unroll
    for (int j = 0; j < 4; j++) acc[i][j] = zero4;

  for (int bk = 0; bk < K; bk += 32) {
// ---- stage A tile (128 x 32 bf16), 8 elems (16B) per thread-chunk ----
#pragma unroll
    for (int c = 0; c < 2; c++) {
      int chunk = t + c * 256;
      int row = chunk >> 2, seg = chunk & 3;
      long long g = (long long)(bm * 128 + row) * lda + bk + seg * 8;
      uint4 v;
      if constexpr (sizeof(TA) == 2) {
        v = *(const uint4*)((const unsigned short*)A + g);
      } else {
        const float* Af = (const float*)A + g;
        float4 f0 = *(const float4*)Af;
        float4 f1 = *(const float4*)(Af + 4);
        v.x = f2bf(f0.x) | (f2bf(f0.y) << 16);
        v.y = f2bf(f0.z) | (f2bf(f0.w) << 16);
        v.z = f2bf(f1.x) | (f2bf(f1.y) << 16);
        v.w = f2bf(f1.z) | (f2bf(f1.w) << 16);
      }
      *(uint4*)(&As[row * 40 + seg * 8]) = v;
    }
// ---- stage B tile (BT rows, guarded on N) ----
#pragma unroll
    for (int c = 0; c < 2; c++) {
      int chunk = t + c * 256;
      int row = chunk >> 2, seg = chunk & 3;
      int nrow = bn * 128 + row;
      uint4 v = make_uint4(0u, 0u, 0u, 0u);
      if (nrow < N) v = *(const uint4*)(B + (long long)nrow * ldb + bk + seg * 8);
      *(uint4*)(&Bs[row * 40 + seg * 8]) = v;
    }
    __syncthreads();

    bf16x8 a[4], b[4];
#pragma unroll
    for (int i = 0; i < 4; i++)
      a[i] = *(const bf16x8*)(&As[(wm * 64 + i * 16 + l15) * 40 + quad * 8]);
#pragma unroll
    for (int j = 0; j < 4; j++)
      b[j] = *(const bf16x8*)(&Bs[(wn * 64 + j * 16 + l15) * 40 + quad * 8]);
#pragma unroll
    for (int i = 0; i < 4; i++)
#pragma unroll
      for (int j = 0; j < 4; j++)
        acc[i][j] = __builtin_amdgcn_mfma_f32_16x16x32_bf16(a[i], b[j], acc[i][j], 0, 0, 0);
    __syncthreads();
  }

// ---- epilogue: C/D layout col = lane&15, row = quad*4 + reg (m89-verified) ----
#pragma unroll
  for (int i = 0; i < 4; i++) {
#pragma unroll
    for (int j = 0; j < 4; j++) {
#pragma unroll
      for (int r = 0; r < 4; r++) {
        int row = bm * 128 + wm * 64 + i * 16 + quad * 4 + r;
        int col = bn * 128 + wn * 64 + j * 16 + l15;
        float v = acc[i][j][r];
        if constexpr (MODE == 0) { // QKV scatter
          v += bias[col];
          int b_ = row >> 10, nseq = row & 1023;
          int wsel = col / DIM, nn = col - wsel * DIM;
          int h = nn >> 6, d = nn & 63;
          long long bh = (long long)b_ * NHEADS + h;
          unsigned short bv = (unsigned short)f2bf(v);
          if (wsel == 0)
            outA[(bh * SEQ + nseq) * HDIM + d] = bv; // q [B,H,N,D]
          else if (wsel == 1)
            outB[(bh * SEQ + nseq) * HDIM + d] = bv; // k [B,H,N,D]
          else
            outC[(bh * HDIM + d) * SEQ + nseq] = bv; // vT [B,H,D,N]
        } else if constexpr (MODE == 1) { // scores -> fp32 probs region
          outF[(long long)z * SEQ * SEQ + (long long)row * SEQ + col] = v * scale;
        } else if constexpr (MODE == 2) { // PV -> o merged [token][h*64+d] bf16
          if (col < N) {
            int b_ = z / NHEADS, h = z - b_ * NHEADS;
            outA[((long long)(b_ * SEQ + row)) * DIM + h * HDIM + col] = (unsigned short)f2bf(v);
          }
        } else { // out projection fp32 + bias
          outF[(long long)row * DIM + col] = v + bias[col];
        }
      }
    }
  }
}

// ---------------- row softmax, in place, 1 wave per row of 1024 ----------------

__global__ __launch_bounds__(256) void softmax_kernel(float* __restrict__ probs) {
  int wid = threadIdx.x >> 6, lane = threadIdx.x & 63;
  long long row = (long long)blockIdx.x * 4 + wid;
  float* p = probs + row * SEQ;
  float4 v[4];
#pragma unroll
  for (int k = 0; k < 4; k++) v[k] = *(const float4*)(p + 4 * (lane + 64 * k));
  float mx = -1e30f;
#pragma unroll
  for (int k = 0; k < 4; k++)
    mx = fmaxf(mx, fmaxf(fmaxf(v[k].x, v[k].y), fmaxf(v[k].z, v[k].w)));
#pragma unroll
  for (int m = 1; m < 64; m <<= 1) mx = fmaxf(mx, __shfl_xor(mx, m, 64));
  float s = 0.f;
#pragma unroll
  for (int k = 0; k < 4; k++) {
    v[k].x = __expf(v[k].x - mx);
    v[k].y = __expf(v[k].y - mx);
    v[k].z = __expf(v[k].z - mx);
    v[k].w = __expf(v[k].w - mx);
    s += v[k].x + v[k].y + v[k].z + v[k].w;
  }
#pragma unroll
  for (int m = 1; m < 64; m <<= 1) s += __shfl_xor(s, m, 64);
  float inv = 1.0f / s;
#pragma unroll
  for (int k = 0; k < 4; k++) {
    v[k].x *= inv;
    v[k].y *= inv;
    v[k].z *= inv;
    v[k].w *= inv;
    *(float4*)(p + 4 * (lane + 64 * k)) = v[k];
  }
}

// ---------------- launch ----------------

extern "C" void kernel_launch(void* const* d_in, const int* in_sizes, int n_in,
                              void* d_out, int out_size, void* d_ws, size_t ws_size,
                              hipStream_t stream) {
  const float* x = (const float*)d_in[0];
  const float* Wq = (const float*)d_in[1];
  const float* bq = (const float*)d_in[2];
  const float* Wk = (const float*)d_in[3];
  const float* bk = (const float*)d_in[4];
  const float* Wv = (const float*)d_in[5];
  const float* bv = (const float*)d_in[6];
  const float* Wo = (const float*)d_in[7];
  const float* bo = (const float*)d_in[8];

  char* ws = (char*)d_ws;
  size_t off = 0;
  auto alloc = [&](size_t bytes) {
    void* p = ws + off;
    off = (off + bytes + 255) & ~(size_t)255;
    return p;
  };
  unsigned short* xb = (unsigned short*)alloc((size_t)TOKENS * DIM * 2);
  unsigned short* WT = (unsigned short*)alloc((size_t)4 * DIM * DIM * 2);
  float* bqkv = (float*)alloc((size_t)NQKV * 4);
  unsigned short* q = (unsigned short*)alloc((size_t)TOKENS * DIM * 2);
  unsigned short* kmat = (unsigned short*)alloc((size_t)TOKENS * DIM * 2);
  unsigned short* vT = (unsigned short*)alloc((size_t)TOKENS * DIM * 2);
  unsigned short* o = (unsigned short*)alloc((size_t)TOKENS * DIM * 2);
  (void)ws_size; // needs ~68 MB

  float* outp = (float*)d_out;
  float* probs = outp + (size_t)TOKENS * DIM; // [B,H,N,N] fp32, 402 MB

  conv_x_kernel<<<(TOKENS * DIM / 4) / 256, 256, 0, stream>>>(x, xb);
  transpose_w_kernel<<<dim3(24, 24, 4), 256, 0, stream>>>(Wq, Wk, Wv, Wo, WT);
  pack_bias_kernel<<<9, 256, 0, stream>>>(bq, bk, bv, bqkv);

  // QKV: M=8192, N=2304, K=768
  gemm_bt_kernel<0, unsigned short><<<dim3(18, 64, 1), 256, 0, stream>>>(
      xb, WT, bqkv, nullptr, q, kmat, vT, TOKENS, NQKV, DIM, DIM, DIM, 0, 0, 0.f);

  // scores: per (b,h), M=N=1024, K=64, *1/sqrt(64)
  gemm_bt_kernel<1, unsigned short><<<dim3(8, 8, 96), 256, 0, stream>>>(
      q, kmat, nullptr, probs, nullptr, nullptr, nullptr, SEQ, SEQ, HDIM, HDIM, HDIM,
      (long long)SEQ * HDIM, (long long)SEQ * HDIM, 0.125f);

  // softmax rows in place
  softmax_kernel<<<(BATCH * NHEADS * SEQ) / 4, 256, 0, stream>>>(probs);

  // PV: per (b,h), M=1024, N=64, K=1024; A = fp32 probs
  gemm_bt_kernel<2, float><<<dim3(1, 8, 96), 256, 0, stream>>>(
      probs, vT, nullptr, nullptr, o, nullptr, nullptr, SEQ, HDIM, SEQ, SEQ, SEQ,
      (long long)SEQ * SEQ, (long long)HDIM * SEQ, 0.f);

  // out projection: M=8192, N=768, K=768, + bo
  gemm_bt_kernel<3, unsigned short><<<dim3(6, 64, 1), 256, 0, stream>>>(
      o, WT + (size_t)3 * DIM * DIM, bo, outp, nullptr, nullptr, nullptr, TOKENS, DIM, DIM,
      DIM, DIM, 0, 0, 0.f);
}